// Round 1
// baseline (291.826 us; speedup 1.0000x reference)
//
#include <hip/hip_runtime.h>
#include <stdint.h>

// ---------- types ----------
typedef short short8 __attribute__((ext_vector_type(8)));
typedef float f32x4 __attribute__((ext_vector_type(4)));

__device__ inline float b2f(unsigned short u) {
    union { float f; uint32_t i; } v; v.i = ((uint32_t)u) << 16; return v.f;
}
__device__ inline unsigned short f2b(float f) {
    union { float f; uint32_t i; } v; v.f = f;
    uint32_t r = v.i + 0x7FFFu + ((v.i >> 16) & 1u);
    return (unsigned short)(r >> 16);
}

// Problem constants
#define BB 8
#define NN 1024
#define HH 128
#define EE 4
#define MROWS (BB * NN)      // 8192
#define NBR_CAP 96

// ---------- weight prep: convert to bf16, build Wc[k][(e,h)] = We[e][k][h] ----------
__global__ __launch_bounds__(256) void prep_w(
    const float* __restrict__ We, const float* __restrict__ Wih,
    const float* __restrict__ Whh, const float* __restrict__ W1,
    const float* __restrict__ W2,
    unsigned short* __restrict__ wc, unsigned short* __restrict__ wih,
    unsigned short* __restrict__ whh, unsigned short* __restrict__ w1,
    unsigned short* __restrict__ w2)
{
    int tid = blockIdx.x * 256 + threadIdx.x;  // grid 256 -> 65536 threads
    if (tid < 65536) {   // Wc: (128 out, 512 in), in-index = e*128+h
        int k = tid >> 9, c = tid & 511;
        int e = c >> 7, hh2 = c & 127;
        wc[tid] = f2b(We[(e << 14) + (k << 7) + hh2]);
    }
    if (tid < 49152) { wih[tid] = f2b(Wih[tid]); whh[tid] = f2b(Whh[tid]); }
    if (tid < 32768) w1[tid] = f2b(W1[tid]);
    if (tid < 16384) w2[tid] = f2b(W2[tid]);
}

// ---------- init: h=nf (f32+bf16), cat[:,0:128]=bf16(nf) ----------
__global__ __launch_bounds__(256) void init_h(
    const float* __restrict__ nf, float* __restrict__ h,
    unsigned short* __restrict__ hb, unsigned short* __restrict__ cat)
{
    int tid = blockIdx.x * 256 + threadIdx.x;  // over MROWS*128
    float v = nf[tid];
    h[tid] = v;
    unsigned short b = f2b(v);
    hb[tid] = b;
    int m = tid >> 7, k = tid & 127;
    cat[(size_t)m * 256 + k] = b;
}

// ---------- sparsify: one wave per (b,e,i) row ----------
__global__ __launch_bounds__(256) void sparsify(
    const float* __restrict__ adj, unsigned short* __restrict__ cols,
    int* __restrict__ cnt)
{
    int row = blockIdx.x * 4 + (threadIdx.x >> 6);  // 32768 rows
    int l = threadIdx.x & 63;
    const float* ar = adj + (size_t)row * NN;
    unsigned short* cr = cols + (size_t)row * NBR_CAP;
    int c = 0;
    for (int it = 0; it < 4; ++it) {
        float4 v = *(const float4*)(ar + it * 256 + l * 4);
        const float* vp = &v.x;
        #pragma unroll
        for (int p = 0; p < 4; ++p) {
            float x = vp[p];
            unsigned long long m = __ballot(x != 0.f);
            if (x != 0.f) {
                int idx = c + __popcll(m & ((1ull << l) - 1ull));
                if (idx < NBR_CAP) cr[idx] = (unsigned short)(it * 256 + l * 4 + p);
            }
            c += __popcll(m);
        }
    }
    if (l == 0) cnt[row] = c < NBR_CAP ? c : NBR_CAP;
}

// ---------- aggregate: a[(b,i), e*128+h] = sum_{j in nbr(b,e,i)} h[b,j,h] ----------
__global__ __launch_bounds__(512) void aggregate(
    const float* __restrict__ hsrc, const unsigned short* __restrict__ cols,
    const int* __restrict__ cnt, unsigned short* __restrict__ a)
{
    int bi = blockIdx.x;            // b*N + i
    int b = bi >> 10, i = bi & 1023;
    int e = threadIdx.x >> 7;
    int hc = threadIdx.x & 127;
    int row = ((b << 2) + e) * NN + i;
    int c = cnt[row];
    const unsigned short* cl = cols + (size_t)row * NBR_CAP;
    float acc = 0.f;
    for (int q = 0; q < c; ++q) {
        int j = cl[q];
        acc += hsrc[((size_t)(b << 10) + j) * HH + hc];
    }
    a[((size_t)bi * EE + e) * HH + hc] = f2b(acc);
}

// ---------- generic bf16 GEMM: C = act(X(MxK) @ W(NxK)^T + bias) ----------
// 64x64 tile, BK=64, 256 threads = 4 waves (2x2), each wave 32x32 (2x2 16x16 frags)
#define LDSP 72   // padded LDS row stride (elements): 144B -> conflict-free b128

template<int ACT, bool BIAS, bool OUTB, bool OUTF>
__global__ __launch_bounds__(256) void gemm_bt(
    const unsigned short* __restrict__ X, const unsigned short* __restrict__ W,
    const float* __restrict__ bias, unsigned short* __restrict__ outb,
    float* __restrict__ outf, int M, int N, int K)
{
    __shared__ unsigned short lx[64 * LDSP];
    __shared__ unsigned short lw[64 * LDSP];
    const int t = threadIdx.x;
    const int l = t & 63;
    const int w = t >> 6;
    const int wr = w >> 1, wc = w & 1;
    const int bm = blockIdx.x * 64;
    const int bn = blockIdx.y * 64;

    f32x4 acc[2][2] = {};
    const int row_s = t >> 3;   // 0..31
    const int ch = t & 7;       // 16B chunk within 128B row

    for (int kb = 0; kb < K; kb += 64) {
        #pragma unroll
        for (int r = 0; r < 2; ++r) {
            int row = r * 32 + row_s;
            short8 vx = *(const short8*)(X + (size_t)(bm + row) * K + kb + ch * 8);
            *(short8*)(&lx[row * LDSP + ch * 8]) = vx;
            short8 vw = *(const short8*)(W + (size_t)(bn + row) * K + kb + ch * 8);
            *(short8*)(&lw[row * LDSP + ch * 8]) = vw;
        }
        __syncthreads();
        #pragma unroll
        for (int kk = 0; kk < 2; ++kk) {
            short8 af[2], bfr[2];
            #pragma unroll
            for (int mi = 0; mi < 2; ++mi) {
                int row = wr * 32 + mi * 16 + (l & 15);
                af[mi] = *(const short8*)(&lx[row * LDSP + kk * 32 + (l >> 4) * 8]);
            }
            #pragma unroll
            for (int ni = 0; ni < 2; ++ni) {
                int row = wc * 32 + ni * 16 + (l & 15);
                bfr[ni] = *(const short8*)(&lw[row * LDSP + kk * 32 + (l >> 4) * 8]);
            }
            #pragma unroll
            for (int mi = 0; mi < 2; ++mi)
                #pragma unroll
                for (int ni = 0; ni < 2; ++ni)
                    acc[mi][ni] = __builtin_amdgcn_mfma_f32_16x16x32_bf16(
                        af[mi], bfr[ni], acc[mi][ni], 0, 0, 0);
        }
        __syncthreads();
    }
    // epilogue: C/D layout col=lane&15, row=(lane>>4)*4+reg
    #pragma unroll
    for (int mi = 0; mi < 2; ++mi)
        #pragma unroll
        for (int ni = 0; ni < 2; ++ni) {
            int col = bn + wc * 32 + ni * 16 + (l & 15);
            float bv = BIAS ? bias[col] : 0.f;
            #pragma unroll
            for (int r = 0; r < 4; ++r) {
                int row = bm + wr * 32 + mi * 16 + (l >> 4) * 4 + r;
                float v = acc[mi][ni][r] + bv;
                if (ACT == 1) v = v > 0.f ? v : 0.f;
                if constexpr (OUTF) outf[(size_t)row * N + col] = v;
                if constexpr (OUTB) outb[(size_t)row * N + col] = f2b(v);
            }
        }
}

// ---------- GRU elementwise ----------
__global__ __launch_bounds__(256) void gru_ew(
    const float* __restrict__ gi, const float* __restrict__ gh,
    float* __restrict__ h, unsigned short* __restrict__ hb)
{
    int tid = blockIdx.x * 256 + threadIdx.x;   // over MROWS*128
    int m = tid >> 7, k = tid & 127;
    const float* gir = gi + (size_t)m * 384;
    const float* ghr = gh + (size_t)m * 384;
    float ir = gir[k], iz = gir[128 + k], in_ = gir[256 + k];
    float hr = ghr[k], hz = ghr[128 + k], hn = ghr[256 + k];
    float r = 1.f / (1.f + __expf(-(ir + hr)));
    float z = 1.f / (1.f + __expf(-(iz + hz)));
    float n = tanhf(in_ + r * hn);
    float ho = h[tid];
    float hv = (1.f - z) * n + z * ho;
    h[tid] = hv;
    hb[tid] = f2b(hv);
}

// ---------- concat h into cat[:,128:256] ----------
__global__ __launch_bounds__(256) void cat_h(
    const unsigned short* __restrict__ hb, unsigned short* __restrict__ cat)
{
    int tid = blockIdx.x * 256 + threadIdx.x;
    int m = tid >> 7, k = tid & 127;
    cat[(size_t)m * 256 + 128 + k] = hb[tid];
}

// ---------- host launcher ----------
extern "C" void kernel_launch(void* const* d_in, const int* in_sizes, int n_in,
                              void* d_out, int out_size, void* d_ws, size_t ws_size,
                              hipStream_t stream) {
    const float* nf  = (const float*)d_in[0];
    const float* adj = (const float*)d_in[1];
    const float* We  = (const float*)d_in[2];
    const float* Wih = (const float*)d_in[3];
    const float* Whh = (const float*)d_in[4];
    const float* bih = (const float*)d_in[5];
    const float* bhh = (const float*)d_in[6];
    const float* W1  = (const float*)d_in[7];
    const float* b1  = (const float*)d_in[8];
    const float* W2  = (const float*)d_in[9];
    const float* b2  = (const float*)d_in[10];
    float* out = (float*)d_out;

    char* p = (char*)d_ws;
    auto take = [&](size_t n) { char* r = p; p += (n + 255) & ~(size_t)255; return r; };
    int* cnt            = (int*)take(32768 * 4);
    unsigned short* cols = (unsigned short*)take((size_t)32768 * NBR_CAP * 2);
    float* h            = (float*)take((size_t)MROWS * 128 * 4);
    unsigned short* hb  = (unsigned short*)take((size_t)MROWS * 128 * 2);
    unsigned short* ab  = (unsigned short*)take((size_t)MROWS * 512 * 2);
    unsigned short* mb  = (unsigned short*)take((size_t)MROWS * 128 * 2);
    float* gi           = (float*)take((size_t)MROWS * 384 * 4);
    float* gh           = (float*)take((size_t)MROWS * 384 * 4);
    unsigned short* cat = (unsigned short*)take((size_t)MROWS * 256 * 2);
    unsigned short* yb  = (unsigned short*)take((size_t)MROWS * 128 * 2);
    unsigned short* wc  = (unsigned short*)take(65536 * 2);
    unsigned short* wih = (unsigned short*)take(49152 * 2);
    unsigned short* whh = (unsigned short*)take(49152 * 2);
    unsigned short* w1  = (unsigned short*)take(32768 * 2);
    unsigned short* w2  = (unsigned short*)take(16384 * 2);

    prep_w<<<256, 256, 0, stream>>>(We, Wih, Whh, W1, W2, wc, wih, whh, w1, w2);
    init_h<<<4096, 256, 0, stream>>>(nf, h, hb, cat);
    sparsify<<<8192, 256, 0, stream>>>(adj, cols, cnt);

    for (int s = 0; s < 3; ++s) {
        aggregate<<<MROWS, 512, 0, stream>>>(h, cols, cnt, ab);
        // m = a @ Wc^T   (8192x512 @ 512x128)
        gemm_bt<0, false, true, false><<<dim3(128, 2), 256, 0, stream>>>(
            ab, wc, nullptr, mb, nullptr, MROWS, 128, 512);
        // gi = m @ W_ih^T + b_ih  (8192x128 -> 384)
        gemm_bt<0, true, false, true><<<dim3(128, 6), 256, 0, stream>>>(
            mb, wih, bih, nullptr, gi, MROWS, 384, 128);
        // gh = h @ W_hh^T + b_hh
        gemm_bt<0, true, false, true><<<dim3(128, 6), 256, 0, stream>>>(
            hb, whh, bhh, nullptr, gh, MROWS, 384, 128);
        gru_ew<<<4096, 256, 0, stream>>>(gi, gh, h, hb);
    }

    cat_h<<<4096, 256, 0, stream>>>(hb, cat);
    // y = relu(cat @ W1^T + b1)  (8192x256 -> 128)
    gemm_bt<1, true, true, false><<<dim3(128, 2), 256, 0, stream>>>(
        cat, w1, b1, yb, nullptr, MROWS, 128, 256);
    // out = y @ W2^T + b2  (8192x128 -> 128)
    gemm_bt<0, true, false, true><<<dim3(128, 2), 256, 0, stream>>>(
        yb, w2, b2, nullptr, out, MROWS, 128, 128);
}

// Round 2
// 181.855 us; speedup vs baseline: 1.6047x; 1.6047x over previous
//
#include <hip/hip_runtime.h>
#include <stdint.h>

typedef short short8 __attribute__((ext_vector_type(8)));
typedef float f32x4 __attribute__((ext_vector_type(4)));

__device__ inline float b2f(unsigned short u) {
    union { float f; uint32_t i; } v; v.i = ((uint32_t)u) << 16; return v.f;
}
__device__ inline unsigned short f2b(float f) {
    union { float f; uint32_t i; } v; v.f = f;
    uint32_t r = v.i + 0x7FFFu + ((v.i >> 16) & 1u);
    return (unsigned short)(r >> 16);
}

#define BB 8
#define NN 1024
#define HH 128
#define EE 4
#define MROWS (BB * NN)      // 8192
#define NBR_CAP 96

// ============ setup: init h/hb/nfb + all weights -> bf16 fragment-major ============
// B-fragment layout for mfma_f32_16x16x32_bf16, N cols, K:
//   wf[(((s*NF + f)*64 + l)*8 + j)] = W[col = f*16 + (l&15)][k = s*32 + (l>>4)*8 + j]
__global__ __launch_bounds__(256) void setup(
    const float* __restrict__ nf, const float* __restrict__ We,
    const float* __restrict__ Wih, const float* __restrict__ Whh,
    const float* __restrict__ bih, const float* __restrict__ bhh,
    const float* __restrict__ W1, const float* __restrict__ W2,
    float* __restrict__ h, unsigned short* __restrict__ hb,
    unsigned short* __restrict__ nfb,
    unsigned short* __restrict__ wcf, unsigned short* __restrict__ wgf,
    unsigned short* __restrict__ w1f, unsigned short* __restrict__ w2f,
    float* __restrict__ bg)
{
    int tid = blockIdx.x * 256 + threadIdx.x;   // 1,048,576 threads
    // ---- state init (all threads) ----
    {
        float v = nf[tid];
        h[tid] = v;
        unsigned short b = f2b(v);
        hb[tid] = b;
        nfb[tid] = b;
    }
    // ---- wgf: Wg(512 x 256) fragment-major (NF=32, s=0..7) ----
    if (tid < 131072) {
        int j = tid & 7, l = (tid >> 3) & 63, f = (tid >> 9) & 31, s = tid >> 14;
        int col = f * 16 + (l & 15);            // 0..511 (gate row)
        int k   = s * 32 + ((l >> 4) << 3) + j; // 0..255
        int kr = k & 127;
        float v;
        if (col < 256)      v = (k < 128) ? Wih[col * 128 + kr] : Whh[col * 128 + kr];
        else if (col < 384) v = (k < 128) ? Wih[col * 128 + kr] : 0.f;
        else                v = (k < 128) ? 0.f : Whh[(col - 128) * 128 + kr];
        wgf[tid] = f2b(v);
    }
    // ---- wcf: Wc(128 x 512) fragment-major (NF=8, s=0..15); Wc[c][(e,hh)]=We[e][c][hh] ----
    if (tid < 65536) {
        int j = tid & 7, l = (tid >> 3) & 63, f = (tid >> 9) & 7, s = tid >> 12;
        int col = f * 16 + (l & 15);            // 0..127
        int k   = s * 32 + ((l >> 4) << 3) + j; // 0..511
        int e = k >> 7, hh2 = k & 127;
        wcf[tid] = f2b(We[(e << 14) + (col << 7) + hh2]);
    }
    // ---- w1f: W1(128 x 256) (NF=8, s=0..7) ----
    if (tid < 32768) {
        int j = tid & 7, l = (tid >> 3) & 63, f = (tid >> 9) & 7, s = tid >> 12;
        int col = f * 16 + (l & 15);
        int k   = s * 32 + ((l >> 4) << 3) + j;
        w1f[tid] = f2b(W1[col * 256 + k]);
    }
    // ---- w2f: W2(128 x 128) (NF=8, s=0..3) ----
    if (tid < 16384) {
        int j = tid & 7, l = (tid >> 3) & 63, f = (tid >> 9) & 7, s = tid >> 12;
        int col = f * 16 + (l & 15);
        int k   = s * 32 + ((l >> 4) << 3) + j;
        w2f[tid] = f2b(W2[col * 128 + k]);
    }
    // ---- bg[512] ----
    if (tid < 512) {
        int sec = tid >> 7, k = tid & 127;
        float v;
        if (sec == 0)      v = bih[k] + bhh[k];
        else if (sec == 1) v = bih[128 + k] + bhh[128 + k];
        else if (sec == 2) v = bih[256 + k];
        else               v = bhh[256 + k];
        bg[tid] = v;
    }
}

// ============ sparsify: one wave per (b,e,i) row ============
__global__ __launch_bounds__(256) void sparsify(
    const float* __restrict__ adj, unsigned short* __restrict__ cols,
    int* __restrict__ cnt)
{
    int row = blockIdx.x * 4 + (threadIdx.x >> 6);  // 32768 rows
    int l = threadIdx.x & 63;
    const float* ar = adj + (size_t)row * NN;
    unsigned short* cr = cols + (size_t)row * NBR_CAP;
    int c = 0;
    for (int it = 0; it < 4; ++it) {
        float4 v = *(const float4*)(ar + it * 256 + l * 4);
        const float* vp = &v.x;
        #pragma unroll
        for (int p = 0; p < 4; ++p) {
            float x = vp[p];
            unsigned long long m = __ballot(x != 0.f);
            if (x != 0.f) {
                int idx = c + __popcll(m & ((1ull << l) - 1ull));
                if (idx < NBR_CAP) cr[idx] = (unsigned short)(it * 256 + l * 4 + p);
            }
            c += __popcll(m);
        }
    }
    if (l == 0) cnt[row] = c < NBR_CAP ? c : NBR_CAP;
}

// ============ aggregate: ab[(b,i), e*128+h] = sum_j hb[b,j,h] (bf16 gather, f32 acc) ============
__global__ __launch_bounds__(256) void aggregate(
    const unsigned short* __restrict__ hb, const unsigned short* __restrict__ cols,
    const int* __restrict__ cnt, unsigned short* __restrict__ ab)
{
    int bi = blockIdx.x;                 // b*N + i
    int b = bi >> 10, i = bi & 1023;
    int e = threadIdx.x >> 6;
    int l2 = (threadIdx.x & 63) * 2;     // 2 cols per lane
    int row = ((b << 2) + e) * NN + i;
    int c = cnt[row];
    const unsigned short* cl = cols + (size_t)row * NBR_CAP;
    const unsigned short* hbase = hb + ((size_t)(b << 10)) * HH + l2;
    float a0 = 0.f, a1 = 0.f;
    for (int q = 0; q < c; ++q) {
        uint32_t v = *(const uint32_t*)(hbase + (size_t)cl[q] * HH);
        a0 += b2f((unsigned short)(v & 0xffffu));
        a1 += b2f((unsigned short)(v >> 16));
    }
    uint32_t pr = (uint32_t)f2b(a0) | ((uint32_t)f2b(a1) << 16);
    *(uint32_t*)(ab + ((size_t)bi * EE + e) * HH + l2) = pr;
}

// ============ combine: mb = ab(8192x512) @ Wc^T -> bf16 (32-row blocks) ============
#define CXP 520
__global__ __launch_bounds__(256) void gemm_m(
    const unsigned short* __restrict__ ab, const unsigned short* __restrict__ wcf,
    unsigned short* __restrict__ mb)
{
    __shared__ unsigned short lx[32 * CXP];
    const int t = threadIdx.x, l = t & 63, w = t >> 6;
    const int bm = blockIdx.x * 32;
    for (int ci = t; ci < 2048; ci += 256) {
        int row = ci >> 6, ch = ci & 63;
        *(short8*)(&lx[row * CXP + ch * 8]) =
            *(const short8*)(ab + (size_t)(bm + row) * 512 + ch * 8);
    }
    __syncthreads();
    f32x4 acc[2][2] = {};
    const int ak = (l >> 4) * 8;
    #pragma unroll
    for (int s = 0; s < 16; ++s) {
        short8 af[2];
        #pragma unroll
        for (int mi = 0; mi < 2; ++mi) {
            int row = mi * 16 + (l & 15);
            af[mi] = *(const short8*)(&lx[row * CXP + s * 32 + ak]);
        }
        #pragma unroll
        for (int ni = 0; ni < 2; ++ni) {
            int f = w * 2 + ni;
            short8 bf = *(const short8*)(wcf + (((size_t)s * 8 + f) * 64 + l) * 8);
            #pragma unroll
            for (int mi = 0; mi < 2; ++mi)
                acc[mi][ni] = __builtin_amdgcn_mfma_f32_16x16x32_bf16(
                    af[mi], bf, acc[mi][ni], 0, 0, 0);
        }
    }
    #pragma unroll
    for (int mi = 0; mi < 2; ++mi)
        #pragma unroll
        for (int ni = 0; ni < 2; ++ni) {
            int col = w * 32 + ni * 16 + (l & 15);
            #pragma unroll
            for (int r = 0; r < 4; ++r) {
                int row = bm + mi * 16 + (l >> 4) * 4 + r;
                mb[(size_t)row * 128 + col] = f2b(acc[mi][ni][r]);
            }
        }
}

// ============ gates+GRU: G = [m|h](K=256) @ Wg^T(512x256), GRU epilogue ============
#define GXP 264
__global__ __launch_bounds__(256) void gates_gru(
    const unsigned short* __restrict__ mb, unsigned short* __restrict__ hb,
    const unsigned short* __restrict__ wgf, const float* __restrict__ bg,
    float* __restrict__ h)
{
    __shared__ unsigned short lx[16 * GXP];   // 8.4 KB
    __shared__ float g[16 * 516];             // 33 KB
    const int t = threadIdx.x, l = t & 63, w = t >> 6;
    const int bm = blockIdx.x * 16;
    // stage X = [m|h] rows bm..bm+15, K=256
    for (int ci = t; ci < 512; ci += 256) {
        int row = ci >> 5, col = (ci & 31) * 8;
        const unsigned short* src = (col < 128)
            ? mb + (size_t)(bm + row) * 128 + col
            : hb + (size_t)(bm + row) * 128 + (col - 128);
        *(short8*)(&lx[row * GXP + col]) = *(const short8*)src;
    }
    __syncthreads();
    f32x4 acc[8] = {};
    const int arow = l & 15;
    const int ak = (l >> 4) * 8;
    #pragma unroll
    for (int s = 0; s < 8; ++s) {
        short8 af = *(const short8*)(&lx[arow * GXP + s * 32 + ak]);
        #pragma unroll
        for (int ni = 0; ni < 8; ++ni) {
            int f = w * 8 + ni;
            short8 bf = *(const short8*)(wgf + (((size_t)s * 32 + f) * 64 + l) * 8);
            acc[ni] = __builtin_amdgcn_mfma_f32_16x16x32_bf16(af, bf, acc[ni], 0, 0, 0);
        }
    }
    // scatter gate pre-activations to LDS (f32)
    #pragma unroll
    for (int ni = 0; ni < 8; ++ni) {
        int col = w * 128 + ni * 16 + (l & 15);
        #pragma unroll
        for (int r = 0; r < 4; ++r) {
            int row = (l >> 4) * 4 + r;
            g[row * 516 + col] = acc[ni][r];
        }
    }
    __syncthreads();
    // GRU elementwise: 16 rows x 128
    for (int it = 0; it < 8; ++it) {
        int idx = it * 256 + t;
        int row = idx >> 7, k = idx & 127;
        float rt = g[row * 516 + k]       + bg[k];
        float zt = g[row * 516 + 128 + k] + bg[128 + k];
        float nn = g[row * 516 + 256 + k] + bg[256 + k];
        float hn = g[row * 516 + 384 + k] + bg[384 + k];
        float rr = 1.f / (1.f + __expf(-rt));
        float zz = 1.f / (1.f + __expf(-zt));
        float n = tanhf(nn + rr * hn);
        size_t gi_ = (size_t)(bm + row) * 128 + k;
        float ho = h[gi_];
        float hv = (1.f - zz) * n + zz * ho;
        h[gi_] = hv;
        hb[gi_] = f2b(hv);
    }
}

// ============ MLP: y = relu([nf|h] @ W1^T + b1); out = y @ W2^T + b2 ============
__global__ __launch_bounds__(256) void mlp(
    const unsigned short* __restrict__ nfb, const unsigned short* __restrict__ hb,
    const unsigned short* __restrict__ w1f, const float* __restrict__ b1,
    const unsigned short* __restrict__ w2f, const float* __restrict__ b2,
    float* __restrict__ out)
{
    __shared__ unsigned short lx[32 * GXP];   // 16.9 KB
    __shared__ unsigned short ly[32 * 136];   // 8.7 KB
    const int t = threadIdx.x, l = t & 63, w = t >> 6;
    const int bm = blockIdx.x * 32;
    for (int ci = t; ci < 1024; ci += 256) {
        int row = ci >> 5, col = (ci & 31) * 8;
        const unsigned short* src = (col < 128)
            ? nfb + (size_t)(bm + row) * 128 + col
            : hb  + (size_t)(bm + row) * 128 + (col - 128);
        *(short8*)(&lx[row * GXP + col]) = *(const short8*)src;
    }
    __syncthreads();
    f32x4 acc[2][2] = {};
    const int ak = (l >> 4) * 8;
    #pragma unroll
    for (int s = 0; s < 8; ++s) {
        short8 af[2];
        #pragma unroll
        for (int mi = 0; mi < 2; ++mi)
            af[mi] = *(const short8*)(&lx[(mi * 16 + (l & 15)) * GXP + s * 32 + ak]);
        #pragma unroll
        for (int ni = 0; ni < 2; ++ni) {
            int f = w * 2 + ni;
            short8 bf = *(const short8*)(w1f + (((size_t)s * 8 + f) * 64 + l) * 8);
            #pragma unroll
            for (int mi = 0; mi < 2; ++mi)
                acc[mi][ni] = __builtin_amdgcn_mfma_f32_16x16x32_bf16(
                    af[mi], bf, acc[mi][ni], 0, 0, 0);
        }
    }
    // y -> LDS (relu + bias, bf16)
    #pragma unroll
    for (int mi = 0; mi < 2; ++mi)
        #pragma unroll
        for (int ni = 0; ni < 2; ++ni) {
            int col = w * 32 + ni * 16 + (l & 15);
            float bv = b1[col];
            #pragma unroll
            for (int r = 0; r < 4; ++r) {
                int row = mi * 16 + (l >> 4) * 4 + r;
                float v = acc[mi][ni][r] + bv;
                ly[row * 136 + col] = f2b(v > 0.f ? v : 0.f);
            }
        }
    __syncthreads();
    f32x4 acc2[2][2] = {};
    #pragma unroll
    for (int s = 0; s < 4; ++s) {
        short8 af[2];
        #pragma unroll
        for (int mi = 0; mi < 2; ++mi)
            af[mi] = *(const short8*)(&ly[(mi * 16 + (l & 15)) * 136 + s * 32 + ak]);
        #pragma unroll
        for (int ni = 0; ni < 2; ++ni) {
            int f = w * 2 + ni;
            short8 bf = *(const short8*)(w2f + (((size_t)s * 8 + f) * 64 + l) * 8);
            #pragma unroll
            for (int mi = 0; mi < 2; ++mi)
                acc2[mi][ni] = __builtin_amdgcn_mfma_f32_16x16x32_bf16(
                    af[mi], bf, acc2[mi][ni], 0, 0, 0);
        }
    }
    #pragma unroll
    for (int mi = 0; mi < 2; ++mi)
        #pragma unroll
        for (int ni = 0; ni < 2; ++ni) {
            int col = w * 32 + ni * 16 + (l & 15);
            float bv = b2[col];
            #pragma unroll
            for (int r = 0; r < 4; ++r) {
                int row = bm + mi * 16 + (l >> 4) * 4 + r;
                out[(size_t)row * 128 + col] = acc2[mi][ni][r] + bv;
            }
        }
}

// ============ host launcher ============
extern "C" void kernel_launch(void* const* d_in, const int* in_sizes, int n_in,
                              void* d_out, int out_size, void* d_ws, size_t ws_size,
                              hipStream_t stream) {
    const float* nf  = (const float*)d_in[0];
    const float* adj = (const float*)d_in[1];
    const float* We  = (const float*)d_in[2];
    const float* Wih = (const float*)d_in[3];
    const float* Whh = (const float*)d_in[4];
    const float* bih = (const float*)d_in[5];
    const float* bhh = (const float*)d_in[6];
    const float* W1  = (const float*)d_in[7];
    const float* b1  = (const float*)d_in[8];
    const float* W2  = (const float*)d_in[9];
    const float* b2  = (const float*)d_in[10];
    float* out = (float*)d_out;

    char* p = (char*)d_ws;
    auto take = [&](size_t n) { char* r = p; p += (n + 255) & ~(size_t)255; return r; };
    int* cnt             = (int*)take(32768 * 4);
    unsigned short* cols = (unsigned short*)take((size_t)32768 * NBR_CAP * 2);
    float* h             = (float*)take((size_t)MROWS * 128 * 4);
    unsigned short* hb   = (unsigned short*)take((size_t)MROWS * 128 * 2);
    unsigned short* nfb  = (unsigned short*)take((size_t)MROWS * 128 * 2);
    unsigned short* ab   = (unsigned short*)take((size_t)MROWS * 512 * 2);
    unsigned short* mb   = (unsigned short*)take((size_t)MROWS * 128 * 2);
    unsigned short* wcf  = (unsigned short*)take(65536 * 2);
    unsigned short* wgf  = (unsigned short*)take(131072 * 2);
    unsigned short* w1f  = (unsigned short*)take(32768 * 2);
    unsigned short* w2f  = (unsigned short*)take(16384 * 2);
    float* bg            = (float*)take(512 * 4);

    setup<<<4096, 256, 0, stream>>>(nf, We, Wih, Whh, bih, bhh, W1, W2,
                                    h, hb, nfb, wcf, wgf, w1f, w2f, bg);
    sparsify<<<8192, 256, 0, stream>>>(adj, cols, cnt);

    for (int s = 0; s < 3; ++s) {
        aggregate<<<MROWS, 256, 0, stream>>>(hb, cols, cnt, ab);
        gemm_m<<<256, 256, 0, stream>>>(ab, wcf, mb);
        gates_gru<<<512, 256, 0, stream>>>(mb, hb, wgf, bg, h);
    }

    mlp<<<256, 256, 0, stream>>>(nfb, hb, w1f, b1, w2f, b2, out);
}